// Round 9
// baseline (328.106 us; speedup 1.0000x reference)
//
#include <hip/hip_runtime.h>

#define SEQ 2048
#define EMB 128
#define KT 64
#define QT 64
#define NT 256      // prep block size
#define NTM 512     // main kernel block size (8 waves)
#define NITER (SEQ / KT)

typedef __attribute__((ext_vector_type(8))) short short8;
typedef __attribute__((ext_vector_type(4))) short sh4;
typedef __attribute__((ext_vector_type(4))) float floatx4;
typedef __attribute__((ext_vector_type(4))) unsigned short ushort4_t;

// Device pass exposes 16x16x16 bf16 MFMA only under the legacy _1k name
// (R6 evidence). Host pass sees neither builtin -> __device__ dummy (R8 OK).
#if __has_builtin(__builtin_amdgcn_mfma_f32_16x16x16_bf16)
#define MFMA16(a, b, c) __builtin_amdgcn_mfma_f32_16x16x16_bf16(a, b, c, 0, 0, 0)
#elif __has_builtin(__builtin_amdgcn_mfma_f32_16x16x16bf16_1k)
#define MFMA16(a, b, c) __builtin_amdgcn_mfma_f32_16x16x16bf16_1k(a, b, c, 0, 0, 0)
#else
__device__ static inline floatx4 MFMA16(sh4, sh4, floatx4 c) { return c; }
#endif

__device__ __forceinline__ unsigned short f2bf(float x) {
  union { float f; unsigned u; } c; c.f = x;
  return (unsigned short)((c.u + 0x7fffu + ((c.u >> 16) & 1u)) >> 16);
}
__device__ __forceinline__ unsigned packbf(float a, float b) {
  return (unsigned)f2bf(a) | ((unsigned)f2bf(b) << 16);
}

// ---- fused pre-pass: K fp32->bf16 cvt  +  V fp32 -> Vt bf16 transpose ----
// (known-good version, 256 threads)
__global__ void prep_kernel(const float* __restrict__ K, unsigned short* __restrict__ Kb,
                            const float* __restrict__ V, unsigned short* __restrict__ Vtb,
                            int nblkK) {
  const int tid = threadIdx.x;
  if ((int)blockIdx.x < nblkK) {
    int i = blockIdx.x * NT + tid;
    float4 v = ((const float4*)K)[i];
    ((ushort4_t*)Kb)[i] = (ushort4_t){f2bf(v.x), f2bf(v.y), f2bf(v.z), f2bf(v.w)};
    return;
  }
  const int rb = blockIdx.x - nblkK;
  const int s0 = (rb & 31) * 64;
  const int e0 = ((rb >> 5) & 1) * 64;
  const int b  = rb >> 6;
  const float* src = V + (size_t)b * SEQ * EMB;
  unsigned short* dst = Vtb + (size_t)b * EMB * SEQ;
  const int k = (tid & 15) * 4;
  const int e = (tid >> 4) * 4;
  const float* vb = src + (size_t)(s0 + k) * EMB + e0 + e;
  float4 r0 = *(const float4*)(vb);
  float4 r1 = *(const float4*)(vb + EMB);
  float4 r2 = *(const float4*)(vb + 2 * EMB);
  float4 r3 = *(const float4*)(vb + 3 * EMB);
  unsigned short* d0 = dst + (size_t)(e0 + e) * SEQ + s0 + k;
  *(ushort4_t*)(d0)           = (ushort4_t){f2bf(r0.x), f2bf(r1.x), f2bf(r2.x), f2bf(r3.x)};
  *(ushort4_t*)(d0 + SEQ)     = (ushort4_t){f2bf(r0.y), f2bf(r1.y), f2bf(r2.y), f2bf(r3.y)};
  *(ushort4_t*)(d0 + 2 * SEQ) = (ushort4_t){f2bf(r0.z), f2bf(r1.z), f2bf(r2.z), f2bf(r3.z)};
  *(ushort4_t*)(d0 + 3 * SEQ) = (ushort4_t){f2bf(r0.w), f2bf(r1.w), f2bf(r2.w), f2bf(r3.w)};
}

// ---- main kernel: R3 structure (V staged in LDS, static 2x-unroll, ping-pong
//      regs, setprio, packbf) but 8 waves/block as 2(wq)x4(wk): per-CU work
//      identical, resident waves 8 -> 16 (2 blocks x 8 waves; LDS 64 KB).
//      Epilogue: serial slab chain wk3->wk2->wk1->wk0. ----
__global__ __launch_bounds__(NTM, 4)
void fattn7(const float* __restrict__ Qp, const unsigned short* __restrict__ Kb,
            const unsigned short* __restrict__ Vtb, float* __restrict__ Op) {
  __shared__ __align__(16) unsigned char smem[65536];
  unsigned short* Ks = (unsigned short*)smem;            // [2][KT][EMB] 32 KB
  unsigned short* Vs = Ks + 2 * KT * EMB;                // [2][EMB][KT] 32 KB
  float* Ored = (float*)smem;                            // [64][132] epilogue alias
  float* lredA = (float*)(smem + 64 * 132 * 4);          // [3][64]

  const int tid  = threadIdx.x;
  const int lane = tid & 63;
  const int w    = tid >> 6;     // 0..7
  const int n16  = lane & 15, quad = lane >> 4;
  const int wq   = w & 1;        // q-half (32 rows)
  const int wk   = w >> 1;       // 0..3 k-quarter (16 cols)
  const int b    = blockIdx.y, q0 = blockIdx.x * QT;
  const size_t bo = (size_t)b * SEQ * EMB;

  auto* ks3 = (__attribute__((address_space(3))) unsigned short*)Ks;
  auto* vs3 = (__attribute__((address_space(3))) unsigned short*)Vs;

  const int krw = tid >> 4, kgs = tid & 15;   // krw 0..31
  const int vrw = tid >> 3, vgs = tid & 7;    // vrw 0..63
  const unsigned short* pK = Kb + bo + (size_t)krw * EMB + (size_t)((kgs ^ (krw & 7)) * 8);
  const unsigned short* pV = Vtb + bo + (size_t)vrw * SEQ + (size_t)((vgs ^ (vrw & 7)) * 8);

  short8 qf[2][4];
#pragma unroll
  for (int nt = 0; nt < 2; ++nt) {
    const float* qr = Qp + bo + (size_t)(q0 + wq * 32 + nt * 16 + n16) * EMB + quad * 8;
#pragma unroll
    for (int e = 0; e < 4; ++e) {
      float4 x = *(const float4*)(qr + e * 32);
      float4 y = *(const float4*)(qr + e * 32 + 4);
      qf[nt][e] = (short8){(short)f2bf(x.x), (short)f2bf(x.y), (short)f2bf(x.z), (short)f2bf(x.w),
                           (short)f2bf(y.x), (short)f2bf(y.y), (short)f2bf(y.z), (short)f2bf(y.w)};
    }
  }

  int koff[4];
#pragma unroll
  for (int e = 0; e < 4; ++e) koff[e] = ((e * 4 + quad) ^ (n16 & 7)) * 8;
  // V A-frag: rows t*16+n16, k-col = wk*16 + quad*4 (within tile)
  const int voff16 = (((wk * 2 + (quad >> 1)) ^ (n16 & 7)) * 8) + (quad & 1) * 4;

  floatx4 o[8][2];
#pragma unroll
  for (int t = 0; t < 8; ++t)
#pragma unroll
    for (int nt = 0; nt < 2; ++nt) o[t][nt] = (floatx4){0.f, 0.f, 0.f, 0.f};
  float lp[2] = {0.f, 0.f};

  const float SCALE = 0.08838834764831845f;
  const float L2E = 1.4426950408889634f;
  const float C1 = SCALE * L2E;

  auto issue = [&](int buf) {
    auto* kb = ks3 + buf * (KT * EMB) + w * 512;
    auto* vb = vs3 + buf * (EMB * KT) + w * 512;
    const unsigned short* gv = pV;
#pragma unroll
    for (int j = 0; j < 2; ++j) {
      __builtin_amdgcn_global_load_lds((const __attribute__((address_space(1))) void*)pK,
                                       (__attribute__((address_space(3))) void*)(kb + j * 4096), 16, 0, 0);
      pK += 4096;
      __builtin_amdgcn_global_load_lds((const __attribute__((address_space(1))) void*)gv,
                                       (__attribute__((address_space(3))) void*)(vb + j * 4096), 16, 0, 0);
      gv += 64 * SEQ;
    }
    pV += KT;
  };

  issue(0);

  // ping-pong state (named, static): B-slots are "prev" for tile 0
  sh4 vstA[8], vstB[8];
  unsigned pstA[2][2], pstB[2][2];
#pragma unroll
  for (int t = 0; t < 8; ++t) vstB[t] = (sh4){0, 0, 0, 0};
#pragma unroll
  for (int nt = 0; nt < 2; ++nt) { pstB[nt][0] = 0; pstB[nt][1] = 0; }

#define FA_BODY(CUR, VC, VP, PC, PP)                                                     \
  {                                                                                      \
    floatx4 s0 = (floatx4){0.f, 0.f, 0.f, 0.f};                                          \
    floatx4 s1 = (floatx4){0.f, 0.f, 0.f, 0.f};                                          \
    const unsigned short* kbase = Ks + (CUR) * (KT * EMB);                               \
    __builtin_amdgcn_s_setprio(1);                                                       \
    _Pragma("unroll") for (int e = 0; e < 4; ++e) {                                      \
      short8 ak = *(const short8*)(kbase + (wk * 16 + n16) * EMB + koff[e]);             \
      s0 = __builtin_amdgcn_mfma_f32_16x16x32_bf16(ak, qf[0][e], s0, 0, 0, 0);           \
      s1 = __builtin_amdgcn_mfma_f32_16x16x32_bf16(ak, qf[1][e], s1, 0, 0, 0);           \
    }                                                                                    \
    const unsigned short* vbase = Vs + (CUR) * (EMB * KT);                               \
    _Pragma("unroll") for (int t = 0; t < 8; ++t)                                        \
      VC[t] = *(const sh4*)(vbase + (t * 16 + n16) * KT + voff16);                       \
    sh4 pb0, pb1;                                                                        \
    {                                                                                    \
      union { unsigned u[2]; sh4 v; } cc;                                                \
      cc.u[0] = PP[0][0]; cc.u[1] = PP[0][1]; pb0 = cc.v;                                \
      cc.u[0] = PP[1][0]; cc.u[1] = PP[1][1]; pb1 = cc.v;                                \
    }                                                                                    \
    _Pragma("unroll") for (int t = 0; t < 8; ++t) {                                      \
      o[t][0] = MFMA16(VP[t], pb0, o[t][0]);                                             \
      o[t][1] = MFMA16(VP[t], pb1, o[t][1]);                                             \
    }                                                                                    \
    __builtin_amdgcn_s_setprio(0);                                                       \
    {                                                                                    \
      float p0 = __builtin_amdgcn_exp2f(s0[0] * C1);                                     \
      float p1 = __builtin_amdgcn_exp2f(s0[1] * C1);                                     \
      float p2 = __builtin_amdgcn_exp2f(s0[2] * C1);                                     \
      float p3 = __builtin_amdgcn_exp2f(s0[3] * C1);                                     \
      lp[0] += (p0 + p1) + (p2 + p3);                                                    \
      PC[0][0] = packbf(p0, p1);                                                         \
      PC[0][1] = packbf(p2, p3);                                                         \
      p0 = __builtin_amdgcn_exp2f(s1[0] * C1);                                           \
      p1 = __builtin_amdgcn_exp2f(s1[1] * C1);                                           \
      p2 = __builtin_amdgcn_exp2f(s1[2] * C1);                                           \
      p3 = __builtin_amdgcn_exp2f(s1[3] * C1);                                           \
      lp[1] += (p0 + p1) + (p2 + p3);                                                    \
      PC[1][0] = packbf(p0, p1);                                                         \
      PC[1][1] = packbf(p2, p3);                                                         \
    }                                                                                    \
  }

  for (int it2 = 0; it2 < NITER / 2; ++it2) {
    __syncthreads();
    issue(1);
    FA_BODY(0, vstA, vstB, pstA, pstB)
    __syncthreads();
    if (it2 + 1 < NITER / 2) issue(0);
    FA_BODY(1, vstB, vstA, pstB, pstA)
  }

  // ---- trailing PV for the last tile (B-slots) ----
  {
    sh4 pb0, pb1;
    union { unsigned u[2]; sh4 v; } cc;
    cc.u[0] = pstB[0][0]; cc.u[1] = pstB[0][1]; pb0 = cc.v;
    cc.u[0] = pstB[1][0]; cc.u[1] = pstB[1][1]; pb1 = cc.v;
#pragma unroll
    for (int t = 0; t < 8; ++t) {
      o[t][0] = MFMA16(vstB[t], pb0, o[t][0]);
      o[t][1] = MFMA16(vstB[t], pb1, o[t][1]);
    }
  }

  // ---- epilogue: lp across quads, then serial slab chain over 4 wk groups ----
#pragma unroll
  for (int nt = 0; nt < 2; ++nt) {
    lp[nt] += __shfl_xor(lp[nt], 16);
    lp[nt] += __shfl_xor(lp[nt], 32);
  }
  const int row0 = wq * 32 + n16;        // nt adds 16
  __syncthreads();
  if (wk == 3) {
#pragma unroll
    for (int t = 0; t < 8; ++t)
#pragma unroll
      for (int nt = 0; nt < 2; ++nt)
        *(floatx4*)&Ored[(row0 + nt * 16) * 132 + t * 16 + quad * 4] = o[t][nt];
    if (quad == 0) {
      lredA[0 * 64 + row0] = lp[0];
      lredA[0 * 64 + row0 + 16] = lp[1];
    }
  }
  __syncthreads();
  if (wk == 2) {
#pragma unroll
    for (int t = 0; t < 8; ++t)
#pragma unroll
      for (int nt = 0; nt < 2; ++nt) {
        float* p = &Ored[(row0 + nt * 16) * 132 + t * 16 + quad * 4];
        floatx4 r = *(const floatx4*)p;
        r[0] += o[t][nt][0]; r[1] += o[t][nt][1]; r[2] += o[t][nt][2]; r[3] += o[t][nt][3];
        *(floatx4*)p = r;
      }
    if (quad == 0) {
      lredA[1 * 64 + row0] = lp[0] + lredA[0 * 64 + row0];
      lredA[1 * 64 + row0 + 16] = lp[1] + lredA[0 * 64 + row0 + 16];
    }
  }
  __syncthreads();
  if (wk == 1) {
#pragma unroll
    for (int t = 0; t < 8; ++t)
#pragma unroll
      for (int nt = 0; nt < 2; ++nt) {
        float* p = &Ored[(row0 + nt * 16) * 132 + t * 16 + quad * 4];
        floatx4 r = *(const floatx4*)p;
        r[0] += o[t][nt][0]; r[1] += o[t][nt][1]; r[2] += o[t][nt][2]; r[3] += o[t][nt][3];
        *(floatx4*)p = r;
      }
    if (quad == 0) {
      lredA[2 * 64 + row0] = lp[0] + lredA[1 * 64 + row0];
      lredA[2 * 64 + row0 + 16] = lp[1] + lredA[1 * 64 + row0 + 16];
    }
  }
  __syncthreads();
  if (wk == 0) {
    float inv[2];
#pragma unroll
    for (int nt = 0; nt < 2; ++nt)
      inv[nt] = 1.0f / (lp[nt] + lredA[2 * 64 + row0 + nt * 16]);
#pragma unroll
    for (int t = 0; t < 8; ++t)
#pragma unroll
      for (int nt = 0; nt < 2; ++nt) {
        floatx4 r = *(const floatx4*)&Ored[(row0 + nt * 16) * 132 + t * 16 + quad * 4];
        const int q = q0 + row0 + nt * 16;
        float4 st = {(o[t][nt][0] + r[0]) * inv[nt], (o[t][nt][1] + r[1]) * inv[nt],
                     (o[t][nt][2] + r[2]) * inv[nt], (o[t][nt][3] + r[3]) * inv[nt]};
        *(float4*)(Op + bo + (size_t)q * EMB + t * 16 + quad * 4) = st;
      }
  }
}

extern "C" void kernel_launch(void* const* d_in, const int* in_sizes, int n_in,
                              void* d_out, int out_size, void* d_ws, size_t ws_size,
                              hipStream_t stream) {
  const float* Q = (const float*)d_in[0];
  const float* K = (const float*)d_in[1];
  const float* V = (const float*)d_in[2];
  float* O = (float*)d_out;
  const int B = in_sizes[0] / (SEQ * EMB);
  const size_t tsz = (size_t)B * SEQ * EMB;

  unsigned short* Kb = (unsigned short*)d_ws;
  unsigned short* Vtb = Kb + tsz;

  const int nblkK = (int)(tsz / 4 / NT);
  const int nblkV = (SEQ / 64) * (EMB / 64) * B;
  prep_kernel<<<nblkK + nblkV, NT, 0, stream>>>(K, Kb, V, Vtb, nblkK);
  fattn7<<<dim3(SEQ / QT, B), NTM, 0, stream>>>(Q, Kb, Vtb, O);
}

// Round 10
// 149.833 us; speedup vs baseline: 2.1898x; 2.1898x over previous
//
#include <hip/hip_runtime.h>

#define SEQ 2048
#define EMB 128
#define KT 64
#define QT 64
#define NT 256      // prep block size
#define NTM 512     // main kernel block size (8 waves)
#define NITER (SEQ / KT)

typedef __attribute__((ext_vector_type(8))) short short8;
typedef __attribute__((ext_vector_type(4))) short sh4;
typedef __attribute__((ext_vector_type(4))) float floatx4;
typedef __attribute__((ext_vector_type(4))) unsigned short ushort4_t;

#if __has_builtin(__builtin_amdgcn_mfma_f32_16x16x16_bf16)
#define MFMA16(a, b, c) __builtin_amdgcn_mfma_f32_16x16x16_bf16(a, b, c, 0, 0, 0)
#elif __has_builtin(__builtin_amdgcn_mfma_f32_16x16x16bf16_1k)
#define MFMA16(a, b, c) __builtin_amdgcn_mfma_f32_16x16x16bf16_1k(a, b, c, 0, 0, 0)
#else
__device__ static inline floatx4 MFMA16(sh4, sh4, floatx4 c) { return c; }
#endif

__device__ __forceinline__ unsigned short f2bf(float x) {
  union { float f; unsigned u; } c; c.f = x;
  return (unsigned short)((c.u + 0x7fffu + ((c.u >> 16) & 1u)) >> 16);
}
__device__ __forceinline__ unsigned packbf(float a, float b) {
  return (unsigned)f2bf(a) | ((unsigned)f2bf(b) << 16);
}

// ---- fused pre-pass: K fp32->bf16 cvt  +  V fp32 -> Vt bf16 transpose ----
__global__ void prep_kernel(const float* __restrict__ K, unsigned short* __restrict__ Kb,
                            const float* __restrict__ V, unsigned short* __restrict__ Vtb,
                            int nblkK) {
  const int tid = threadIdx.x;
  if ((int)blockIdx.x < nblkK) {
    int i = blockIdx.x * NT + tid;
    float4 v = ((const float4*)K)[i];
    ((ushort4_t*)Kb)[i] = (ushort4_t){f2bf(v.x), f2bf(v.y), f2bf(v.z), f2bf(v.w)};
    return;
  }
  const int rb = blockIdx.x - nblkK;
  const int s0 = (rb & 31) * 64;
  const int e0 = ((rb >> 5) & 1) * 64;
  const int b  = rb >> 6;
  const float* src = V + (size_t)b * SEQ * EMB;
  unsigned short* dst = Vtb + (size_t)b * EMB * SEQ;
  const int k = (tid & 15) * 4;
  const int e = (tid >> 4) * 4;
  const float* vb = src + (size_t)(s0 + k) * EMB + e0 + e;
  float4 r0 = *(const float4*)(vb);
  float4 r1 = *(const float4*)(vb + EMB);
  float4 r2 = *(const float4*)(vb + 2 * EMB);
  float4 r3 = *(const float4*)(vb + 3 * EMB);
  unsigned short* d0 = dst + (size_t)(e0 + e) * SEQ + s0 + k;
  *(ushort4_t*)(d0)           = (ushort4_t){f2bf(r0.x), f2bf(r1.x), f2bf(r2.x), f2bf(r3.x)};
  *(ushort4_t*)(d0 + SEQ)     = (ushort4_t){f2bf(r0.y), f2bf(r1.y), f2bf(r2.y), f2bf(r3.y)};
  *(ushort4_t*)(d0 + 2 * SEQ) = (ushort4_t){f2bf(r0.z), f2bf(r1.z), f2bf(r2.z), f2bf(r3.z)};
  *(ushort4_t*)(d0 + 3 * SEQ) = (ushort4_t){f2bf(r0.w), f2bf(r1.w), f2bf(r2.w), f2bf(r3.w)};
}

// ---- main kernel: R3 structure, 8 waves/block as 4(wq: 16 q-rows) x 2(wk:
//      32 k-cols). Per-wave regs ~117 (o[8]=32 AGPR, qf[4]=16, vst=32) fits
//      the 128 cap at 4 waves/SIMD -> 16 waves/CU, no spill (R9 lesson).
//      Per-CU work identical to R3. Epilogue: 2-slab wk reduce. ----
__global__ __launch_bounds__(NTM, 4)
void fattn7(const float* __restrict__ Qp, const unsigned short* __restrict__ Kb,
            const unsigned short* __restrict__ Vtb, float* __restrict__ Op) {
  __shared__ __align__(16) unsigned char smem[65536];
  unsigned short* Ks = (unsigned short*)smem;            // [2][KT][EMB] 32 KB
  unsigned short* Vs = Ks + 2 * KT * EMB;                // [2][EMB][KT] 32 KB
  float* Ored = (float*)smem;                            // [64][132] epilogue alias
  float* lredA = (float*)(smem + 64 * 132 * 4);          // [64]

  const int tid  = threadIdx.x;
  const int lane = tid & 63;
  const int w    = tid >> 6;     // 0..7
  const int n16  = lane & 15, quad = lane >> 4;
  const int wq   = w & 3;        // q-quarter: 16 rows
  const int wk   = w >> 2;       // k-half: 32 cols
  const int b    = blockIdx.y, q0 = blockIdx.x * QT;
  const size_t bo = (size_t)b * SEQ * EMB;

  auto* ks3 = (__attribute__((address_space(3))) unsigned short*)Ks;
  auto* vs3 = (__attribute__((address_space(3))) unsigned short*)Vs;

  const int krw = tid >> 4, kgs = tid & 15;   // 32 K-rows per issue step
  const int vrw = tid >> 3, vgs = tid & 7;    // 64 V-rows per issue step
  const unsigned short* pK = Kb + bo + (size_t)krw * EMB + (size_t)((kgs ^ (krw & 7)) * 8);
  const unsigned short* pV = Vtb + bo + (size_t)vrw * SEQ + (size_t)((vgs ^ (vrw & 7)) * 8);

  // Q frags: rows q0 + wq*16 + n16
  short8 qf[4];
  {
    const float* qr = Qp + bo + (size_t)(q0 + wq * 16 + n16) * EMB + quad * 8;
#pragma unroll
    for (int e = 0; e < 4; ++e) {
      float4 x = *(const float4*)(qr + e * 32);
      float4 y = *(const float4*)(qr + e * 32 + 4);
      qf[e] = (short8){(short)f2bf(x.x), (short)f2bf(x.y), (short)f2bf(x.z), (short)f2bf(x.w),
                       (short)f2bf(y.x), (short)f2bf(y.y), (short)f2bf(y.z), (short)f2bf(y.w)};
    }
  }

  int koff[4];
#pragma unroll
  for (int e = 0; e < 4; ++e) koff[e] = ((e * 4 + quad) ^ (n16 & 7)) * 8;
  // V A-frag: row e = t*16+n16, k-col = wk*32 + mt*16 + quad*4 (R3 formula)
  int voff16[2];
#pragma unroll
  for (int mt = 0; mt < 2; ++mt)
    voff16[mt] = (((wk * 4 + mt * 2 + (quad >> 1)) ^ (n16 & 7)) * 8) + (quad & 1) * 4;

  floatx4 o[8];
#pragma unroll
  for (int t = 0; t < 8; ++t) o[t] = (floatx4){0.f, 0.f, 0.f, 0.f};
  float lp = 0.f;

  const float SCALE = 0.08838834764831845f;
  const float L2E = 1.4426950408889634f;
  const float C1 = SCALE * L2E;

  auto issue = [&](int buf) {
    auto* kb = ks3 + buf * (KT * EMB) + w * 512;
    auto* vb = vs3 + buf * (EMB * KT) + w * 512;
    const unsigned short* gv = pV;
#pragma unroll
    for (int j = 0; j < 2; ++j) {
      __builtin_amdgcn_global_load_lds((const __attribute__((address_space(1))) void*)pK,
                                       (__attribute__((address_space(3))) void*)(kb + j * 4096), 16, 0, 0);
      pK += 4096;
      __builtin_amdgcn_global_load_lds((const __attribute__((address_space(1))) void*)gv,
                                       (__attribute__((address_space(3))) void*)(vb + j * 4096), 16, 0, 0);
      gv += 64 * SEQ;
    }
    pV += KT;
  };

  issue(0);

  // named ping-pong state: B-slots are "prev" for tile 0
  sh4 vstA[8][2], vstB[8][2];
  unsigned pstA[2][2], pstB[2][2];
#pragma unroll
  for (int t = 0; t < 8; ++t)
#pragma unroll
    for (int mt = 0; mt < 2; ++mt) vstB[t][mt] = (sh4){0, 0, 0, 0};
#pragma unroll
  for (int mt = 0; mt < 2; ++mt) { pstB[mt][0] = 0; pstB[mt][1] = 0; }

#define FA_BODY(CUR, VC, VP, PC, PP)                                                     \
  {                                                                                      \
    floatx4 s0 = (floatx4){0.f, 0.f, 0.f, 0.f};                                          \
    floatx4 s1 = (floatx4){0.f, 0.f, 0.f, 0.f};                                          \
    const unsigned short* kbase = Ks + (CUR) * (KT * EMB);                               \
    __builtin_amdgcn_s_setprio(1);                                                       \
    _Pragma("unroll") for (int e = 0; e < 4; ++e) {                                      \
      short8 ak0 = *(const short8*)(kbase + (wk * 32 + n16) * EMB + koff[e]);            \
      s0 = __builtin_amdgcn_mfma_f32_16x16x32_bf16(ak0, qf[e], s0, 0, 0, 0);             \
      short8 ak1 = *(const short8*)(kbase + (wk * 32 + 16 + n16) * EMB + koff[e]);       \
      s1 = __builtin_amdgcn_mfma_f32_16x16x32_bf16(ak1, qf[e], s1, 0, 0, 0);             \
    }                                                                                    \
    const unsigned short* vbase = Vs + (CUR) * (EMB * KT);                               \
    _Pragma("unroll") for (int t = 0; t < 8; ++t) {                                      \
      VC[t][0] = *(const sh4*)(vbase + (t * 16 + n16) * KT + voff16[0]);                 \
      VC[t][1] = *(const sh4*)(vbase + (t * 16 + n16) * KT + voff16[1]);                 \
    }                                                                                    \
    sh4 pb0, pb1;                                                                        \
    {                                                                                    \
      union { unsigned u[2]; sh4 v; } cc;                                                \
      cc.u[0] = PP[0][0]; cc.u[1] = PP[0][1]; pb0 = cc.v;                                \
      cc.u[0] = PP[1][0]; cc.u[1] = PP[1][1]; pb1 = cc.v;                                \
    }                                                                                    \
    _Pragma("unroll") for (int t = 0; t < 8; ++t) {                                      \
      o[t] = MFMA16(VP[t][0], pb0, o[t]);                                                \
      o[t] = MFMA16(VP[t][1], pb1, o[t]);                                                \
    }                                                                                    \
    __builtin_amdgcn_s_setprio(0);                                                       \
    {                                                                                    \
      float p0 = __builtin_amdgcn_exp2f(s0[0] * C1);                                     \
      float p1 = __builtin_amdgcn_exp2f(s0[1] * C1);                                     \
      float p2 = __builtin_amdgcn_exp2f(s0[2] * C1);                                     \
      float p3 = __builtin_amdgcn_exp2f(s0[3] * C1);                                     \
      lp += (p0 + p1) + (p2 + p3);                                                       \
      PC[0][0] = packbf(p0, p1);                                                         \
      PC[0][1] = packbf(p2, p3);                                                         \
      p0 = __builtin_amdgcn_exp2f(s1[0] * C1);                                           \
      p1 = __builtin_amdgcn_exp2f(s1[1] * C1);                                           \
      p2 = __builtin_amdgcn_exp2f(s1[2] * C1);                                           \
      p3 = __builtin_amdgcn_exp2f(s1[3] * C1);                                           \
      lp += (p0 + p1) + (p2 + p3);                                                       \
      PC[1][0] = packbf(p0, p1);                                                         \
      PC[1][1] = packbf(p2, p3);                                                         \
    }                                                                                    \
  }

  for (int it2 = 0; it2 < NITER / 2; ++it2) {
    __syncthreads();
    issue(1);
    FA_BODY(0, vstA, vstB, pstA, pstB)
    __syncthreads();
    if (it2 + 1 < NITER / 2) issue(0);
    FA_BODY(1, vstB, vstA, pstB, pstA)
  }

  // ---- trailing PV for the last tile (B-slots) ----
  {
    sh4 pb0, pb1;
    union { unsigned u[2]; sh4 v; } cc;
    cc.u[0] = pstB[0][0]; cc.u[1] = pstB[0][1]; pb0 = cc.v;
    cc.u[0] = pstB[1][0]; cc.u[1] = pstB[1][1]; pb1 = cc.v;
#pragma unroll
    for (int t = 0; t < 8; ++t) {
      o[t] = MFMA16(vstB[t][0], pb0, o[t]);
      o[t] = MFMA16(vstB[t][1], pb1, o[t]);
    }
  }

  // ---- epilogue: lp across quads, then 2-slab wk reduce ----
  lp += __shfl_xor(lp, 16);
  lp += __shfl_xor(lp, 32);
  const int row0 = wq * 16 + n16;   // 0..63, distinct per wq
  __syncthreads();
  if (wk == 1) {
#pragma unroll
    for (int t = 0; t < 8; ++t)
      *(floatx4*)&Ored[row0 * 132 + t * 16 + quad * 4] = o[t];
    if (quad == 0) lredA[row0] = lp;
  }
  __syncthreads();
  if (wk == 0) {
    const float inv = 1.0f / (lp + lredA[row0]);
    const int q = q0 + row0;
#pragma unroll
    for (int t = 0; t < 8; ++t) {
      floatx4 r = *(const floatx4*)&Ored[row0 * 132 + t * 16 + quad * 4];
      float4 st = {(o[t][0] + r[0]) * inv, (o[t][1] + r[1]) * inv,
                   (o[t][2] + r[2]) * inv, (o[t][3] + r[3]) * inv};
      *(float4*)(Op + bo + (size_t)q * EMB + t * 16 + quad * 4) = st;
    }
  }
}

extern "C" void kernel_launch(void* const* d_in, const int* in_sizes, int n_in,
                              void* d_out, int out_size, void* d_ws, size_t ws_size,
                              hipStream_t stream) {
  const float* Q = (const float*)d_in[0];
  const float* K = (const float*)d_in[1];
  const float* V = (const float*)d_in[2];
  float* O = (float*)d_out;
  const int B = in_sizes[0] / (SEQ * EMB);
  const size_t tsz = (size_t)B * SEQ * EMB;

  unsigned short* Kb = (unsigned short*)d_ws;
  unsigned short* Vtb = Kb + tsz;

  const int nblkK = (int)(tsz / 4 / NT);
  const int nblkV = (SEQ / 64) * (EMB / 64) * B;
  prep_kernel<<<nblkK + nblkV, NT, 0, stream>>>(K, Kb, V, Vtb, nblkK);
  fattn7<<<dim3(SEQ / QT, B), NTM, 0, stream>>>(Q, Kb, Vtb, O);
}

// Round 12
// 141.052 us; speedup vs baseline: 2.3261x; 1.0623x over previous
//
#include <hip/hip_runtime.h>

#define SEQ 2048
#define EMB 128
#define KT 64
#define QT 64
#define NT 256
#define NITER (SEQ / KT)

typedef __attribute__((ext_vector_type(8))) short short8;
typedef __attribute__((ext_vector_type(4))) short sh4;
typedef __attribute__((ext_vector_type(4))) float floatx4;
typedef __attribute__((ext_vector_type(4))) unsigned short ushort4_t;

#if __has_builtin(__builtin_amdgcn_mfma_f32_16x16x16_bf16)
#define MFMA16(a, b, c) __builtin_amdgcn_mfma_f32_16x16x16_bf16(a, b, c, 0, 0, 0)
#elif __has_builtin(__builtin_amdgcn_mfma_f32_16x16x16bf16_1k)
#define MFMA16(a, b, c) __builtin_amdgcn_mfma_f32_16x16x16bf16_1k(a, b, c, 0, 0, 0)
#else
__device__ static inline floatx4 MFMA16(sh4, sh4, floatx4 c) { return c; }
#endif

__device__ __forceinline__ unsigned short f2bf(float x) {
  union { float f; unsigned u; } c; c.f = x;
  return (unsigned short)((c.u + 0x7fffu + ((c.u >> 16) & 1u)) >> 16);
}
__device__ __forceinline__ unsigned packbf(float a, float b) {
  return (unsigned)f2bf(a) | ((unsigned)f2bf(b) << 16);
}

// ---- fused pre-pass: K fp32->bf16 cvt  +  V fp32 -> Vt bf16 transpose ----
// DELTA vs R3: V columns permuted within each 64-tile so a PV lane's 8 shorts
// (mt0 quad-chunk + mt1 quad-chunk) are contiguous: col' = g*32+quad*8+mt*4+j.
__global__ void prep_kernel(const float* __restrict__ K, unsigned short* __restrict__ Kb,
                            const float* __restrict__ V, unsigned short* __restrict__ Vtb,
                            int nblkK) {
  const int tid = threadIdx.x;
  if ((int)blockIdx.x < nblkK) {
    int i = blockIdx.x * NT + tid;
    float4 v = ((const float4*)K)[i];
    ((ushort4_t*)Kb)[i] = (ushort4_t){f2bf(v.x), f2bf(v.y), f2bf(v.z), f2bf(v.w)};
    return;
  }
  const int rb = blockIdx.x - nblkK;
  const int s0 = (rb & 31) * 64;
  const int e0 = ((rb >> 5) & 1) * 64;
  const int b  = rb >> 6;
  const float* src = V + (size_t)b * SEQ * EMB;
  unsigned short* dst = Vtb + (size_t)b * EMB * SEQ;
  const int k = (tid & 15) * 4;      // 4-aligned within 64-tile
  const int e = (tid >> 4) * 4;
  // col permutation (k&3 == 0): g*32 + quad*8 + mt*4  (from g*32 + mt*16 + quad*4)
  const int kp = (k & 32) + (((k >> 2) & 3) * 8) + (((k >> 4) & 1) * 4);
  const float* vb = src + (size_t)(s0 + k) * EMB + e0 + e;
  float4 r0 = *(const float4*)(vb);
  float4 r1 = *(const float4*)(vb + EMB);
  float4 r2 = *(const float4*)(vb + 2 * EMB);
  float4 r3 = *(const float4*)(vb + 3 * EMB);
  unsigned short* d0 = dst + (size_t)(e0 + e) * SEQ + s0 + kp;
  *(ushort4_t*)(d0)           = (ushort4_t){f2bf(r0.x), f2bf(r1.x), f2bf(r2.x), f2bf(r3.x)};
  *(ushort4_t*)(d0 + SEQ)     = (ushort4_t){f2bf(r0.y), f2bf(r1.y), f2bf(r2.y), f2bf(r3.y)};
  *(ushort4_t*)(d0 + 2 * SEQ) = (ushort4_t){f2bf(r0.z), f2bf(r1.z), f2bf(r2.z), f2bf(r3.z)};
  *(ushort4_t*)(d0 + 3 * SEQ) = (ushort4_t){f2bf(r0.w), f2bf(r1.w), f2bf(r2.w), f2bf(r3.w)};
}

// ---- main kernel: R3 structure (4 waves 2x2, V staged in LDS, static
//      2x-unroll, ping-pong regs, setprio, packbf). DELTA vs R3: V-frag LDS
//      reads are ds_read_b128 (8/tile, conflict-free XOR pattern) instead of
//      16 conflicted ds_read_b64 — enabled by prep's column permutation. ----
__global__ __launch_bounds__(NT, 2)
void fattn7(const float* __restrict__ Qp, const unsigned short* __restrict__ Kb,
            const unsigned short* __restrict__ Vtb, float* __restrict__ Op) {
  __shared__ __align__(16) unsigned char smem[65536];
  unsigned short* Ks = (unsigned short*)smem;            // [2][KT][EMB] 32 KB
  unsigned short* Vs = Ks + 2 * KT * EMB;                // [2][EMB][KT] 32 KB
  float* Ored = (float*)smem;                            // [2][32][132] (epilogue alias)
  float* lred = (float*)(smem + 2 * 32 * 132 * 4);       // [2][32]

  const int tid  = threadIdx.x;
  const int lane = tid & 63;
  const int w    = tid >> 6;
  const int n16  = lane & 15, quad = lane >> 4;
  const int wq   = w & 1;
  const int wk   = w >> 1;
  const int b    = blockIdx.y, q0 = blockIdx.x * QT;
  const size_t bo = (size_t)b * SEQ * EMB;

  auto* ks3 = (__attribute__((address_space(3))) unsigned short*)Ks;
  auto* vs3 = (__attribute__((address_space(3))) unsigned short*)Vs;

  const int krw = tid >> 4, kgs = tid & 15;
  const int vrw = tid >> 3, vgs = tid & 7;
  const unsigned short* pK = Kb + bo + (size_t)krw * EMB + (size_t)((kgs ^ (krw & 7)) * 8);
  const unsigned short* pV = Vtb + bo + (size_t)vrw * SEQ + (size_t)((vgs ^ (vrw & 7)) * 8);

  short8 qf[2][4];
#pragma unroll
  for (int nt = 0; nt < 2; ++nt) {
    const float* qr = Qp + bo + (size_t)(q0 + wq * 32 + nt * 16 + n16) * EMB + quad * 8;
#pragma unroll
    for (int e = 0; e < 4; ++e) {
      float4 x = *(const float4*)(qr + e * 32);
      float4 y = *(const float4*)(qr + e * 32 + 4);
      qf[nt][e] = (short8){(short)f2bf(x.x), (short)f2bf(x.y), (short)f2bf(x.z), (short)f2bf(x.w),
                           (short)f2bf(y.x), (short)f2bf(y.y), (short)f2bf(y.z), (short)f2bf(y.w)};
    }
  }

  int koff[4];
#pragma unroll
  for (int e = 0; e < 4; ++e) koff[e] = ((e * 4 + quad) ^ (n16 & 7)) * 8;
  // V b128 read: global 16B-chunk (wk*4+quad) of row t*16+n16, XOR staging swizzle
  const int voff = ((wk * 4 + quad) ^ (n16 & 7)) * 8;

  floatx4 o[8][2];
#pragma unroll
  for (int t = 0; t < 8; ++t)
#pragma unroll
    for (int nt = 0; nt < 2; ++nt) o[t][nt] = (floatx4){0.f, 0.f, 0.f, 0.f};
  float lp[2] = {0.f, 0.f};

  const float SCALE = 0.08838834764831845f;
  const float L2E = 1.4426950408889634f;
  const float C1 = SCALE * L2E;

  auto issue = [&](int buf) {
    auto* kb = ks3 + buf * (KT * EMB) + w * 512;
    auto* vb = vs3 + buf * (EMB * KT) + w * 512;
    const unsigned short* gv = pV;
#pragma unroll
    for (int j = 0; j < 4; ++j) {
      __builtin_amdgcn_global_load_lds((const __attribute__((address_space(1))) void*)pK,
                                       (__attribute__((address_space(3))) void*)(kb + j * 2048), 16, 0, 0);
      pK += 2048;
      __builtin_amdgcn_global_load_lds((const __attribute__((address_space(1))) void*)gv,
                                       (__attribute__((address_space(3))) void*)(vb + j * 2048), 16, 0, 0);
      gv += 32 * SEQ;
    }
    pV += KT;
  };

  issue(0);

  // named ping-pong state: B-slots are "prev" for tile 0
  short8 vstA[8], vstB[8];
  unsigned pstA[2][2][2], pstB[2][2][2];
#pragma unroll
  for (int t = 0; t < 8; ++t) vstB[t] = (short8){0, 0, 0, 0, 0, 0, 0, 0};
#pragma unroll
  for (int mt = 0; mt < 2; ++mt)
#pragma unroll
    for (int nt = 0; nt < 2; ++nt) { pstB[mt][nt][0] = 0; pstB[mt][nt][1] = 0; }

#define FA_BODY(CUR, VC, VP, PC, PP)                                                     \
  {                                                                                      \
    floatx4 s[2][2];                                                                     \
    _Pragma("unroll") for (int mt = 0; mt < 2; ++mt)                                     \
      _Pragma("unroll") for (int nt = 0; nt < 2; ++nt)                                   \
        s[mt][nt] = (floatx4){0.f, 0.f, 0.f, 0.f};                                       \
    const unsigned short* kbase = Ks + (CUR) * (KT * EMB);                               \
    __builtin_amdgcn_s_setprio(1);                                                       \
    _Pragma("unroll") for (int e = 0; e < 4; ++e) {                                      \
      _Pragma("unroll") for (int mt = 0; mt < 2; ++mt) {                                 \
        short8 ak = *(const short8*)(kbase + (wk * 32 + mt * 16 + n16) * EMB + koff[e]); \
        s[mt][0] = __builtin_amdgcn_mfma_f32_16x16x32_bf16(ak, qf[0][e], s[mt][0], 0, 0, 0); \
        s[mt][1] = __builtin_amdgcn_mfma_f32_16x16x32_bf16(ak, qf[1][e], s[mt][1], 0, 0, 0); \
      }                                                                                  \
    }                                                                                    \
    const unsigned short* vbase = Vs + (CUR) * (EMB * KT);                               \
    _Pragma("unroll") for (int t = 0; t < 8; ++t)                                        \
      VC[t] = *(const short8*)(vbase + (t * 16 + n16) * KT + voff);                      \
    sh4 pb[2][2];                                                                        \
    _Pragma("unroll") for (int mt = 0; mt < 2; ++mt)                                     \
      _Pragma("unroll") for (int nt = 0; nt < 2; ++nt) {                                 \
        union { unsigned u[2]; sh4 v; } cc;                                              \
        cc.u[0] = PP[mt][nt][0];                                                         \
        cc.u[1] = PP[mt][nt][1];                                                         \
        pb[mt][nt] = cc.v;                                                               \
      }                                                                                  \
    _Pragma("unroll") for (int t = 0; t < 8; ++t) {                                      \
      sh4 vlo = __builtin_shufflevector(VP[t], VP[t], 0, 1, 2, 3);                       \
      sh4 vhi = __builtin_shufflevector(VP[t], VP[t], 4, 5, 6, 7);                       \
      _Pragma("unroll") for (int nt = 0; nt < 2; ++nt) {                                 \
        o[t][nt] = MFMA16(vlo, pb[0][nt], o[t][nt]);                                     \
        o[t][nt] = MFMA16(vhi, pb[1][nt], o[t][nt]);                                     \
      }                                                                                  \
    }                                                                                    \
    __builtin_amdgcn_s_setprio(0);                                                       \
    _Pragma("unroll") for (int mt = 0; mt < 2; ++mt)                                     \
      _Pragma("unroll") for (int nt = 0; nt < 2; ++nt) {                                 \
        float p0 = __builtin_amdgcn_exp2f(s[mt][nt][0] * C1);                            \
        float p1 = __builtin_amdgcn_exp2f(s[mt][nt][1] * C1);                            \
        float p2 = __builtin_amdgcn_exp2f(s[mt][nt][2] * C1);                            \
        float p3 = __builtin_amdgcn_exp2f(s[mt][nt][3] * C1);                            \
        lp[nt] += (p0 + p1) + (p2 + p3);                                                 \
        PC[mt][nt][0] = packbf(p0, p1);                                                  \
        PC[mt][nt][1] = packbf(p2, p3);                                                  \
      }                                                                                  \
  }

  for (int it2 = 0; it2 < NITER / 2; ++it2) {
    __syncthreads();
    issue(1);
    FA_BODY(0, vstA, vstB, pstA, pstB)
    __syncthreads();
    if (it2 + 1 < NITER / 2) issue(0);
    FA_BODY(1, vstB, vstA, pstB, pstA)
  }

  // ---- trailing PV for the last tile (B-slots) ----
  {
    sh4 pb[2][2];
#pragma unroll
    for (int mt = 0; mt < 2; ++mt)
#pragma unroll
      for (int nt = 0; nt < 2; ++nt) {
        union { unsigned u[2]; sh4 v; } cc;
        cc.u[0] = pstB[mt][nt][0];
        cc.u[1] = pstB[mt][nt][1];
        pb[mt][nt] = cc.v;
      }
#pragma unroll
    for (int t = 0; t < 8; ++t) {
      sh4 vlo = __builtin_shufflevector(vstB[t], vstB[t], 0, 1, 2, 3);
      sh4 vhi = __builtin_shufflevector(vstB[t], vstB[t], 4, 5, 6, 7);
#pragma unroll
      for (int nt = 0; nt < 2; ++nt) {
        o[t][nt] = MFMA16(vlo, pb[0][nt], o[t][nt]);
        o[t][nt] = MFMA16(vhi, pb[1][nt], o[t][nt]);
      }
    }
  }

  // ---- epilogue: reduce across k-halves via LDS (aliased over staging) ----
#pragma unroll
  for (int nt = 0; nt < 2; ++nt) {
    lp[nt] += __shfl_xor(lp[nt], 16);
    lp[nt] += __shfl_xor(lp[nt], 32);
  }
  __syncthreads();
  if (wk) {
#pragma unroll
    for (int t = 0; t < 8; ++t)
#pragma unroll
      for (int nt = 0; nt < 2; ++nt)
        *(floatx4*)&Ored[((wq * 32) + nt * 16 + n16) * 132 + t * 16 + quad * 4] = o[t][nt];
    if (quad == 0) {
      lred[wq * 32 + n16] = lp[0];
      lred[wq * 32 + 16 + n16] = lp[1];
    }
  }
  __syncthreads();
  if (!wk) {
    float inv[2];
#pragma unroll
    for (int nt = 0; nt < 2; ++nt)
      inv[nt] = 1.0f / (lp[nt] + lred[wq * 32 + nt * 16 + n16]);
#pragma unroll
    for (int t = 0; t < 8; ++t)
#pragma unroll
      for (int nt = 0; nt < 2; ++nt) {
        floatx4 r = *(const floatx4*)&Ored[((wq * 32) + nt * 16 + n16) * 132 + t * 16 + quad * 4];
        const int q = q0 + wq * 32 + nt * 16 + n16;
        float4 st = {(o[t][nt][0] + r[0]) * inv[nt], (o[t][nt][1] + r[1]) * inv[nt],
                     (o[t][nt][2] + r[2]) * inv[nt], (o[t][nt][3] + r[3]) * inv[nt]};
        *(float4*)(Op + bo + (size_t)q * EMB + t * 16 + quad * 4) = st;
      }
  }
}

extern "C" void kernel_launch(void* const* d_in, const int* in_sizes, int n_in,
                              void* d_out, int out_size, void* d_ws, size_t ws_size,
                              hipStream_t stream) {
  const float* Q = (const float*)d_in[0];
  const float* K = (const float*)d_in[1];
  const float* V = (const float*)d_in[2];
  float* O = (float*)d_out;
  const int B = in_sizes[0] / (SEQ * EMB);
  const size_t tsz = (size_t)B * SEQ * EMB;

  unsigned short* Kb = (unsigned short*)d_ws;
  unsigned short* Vtb = Kb + tsz;

  const int nblkK = (int)(tsz / 4 / NT);
  const int nblkV = (SEQ / 64) * (EMB / 64) * B;
  prep_kernel<<<nblkK + nblkV, NT, 0, stream>>>(K, Kb, V, Vtb, nblkK);
  fattn7<<<dim3(SEQ / QT, B), NT, 0, stream>>>(Q, Kb, Vtb, O);
}

// Round 13
// 139.269 us; speedup vs baseline: 2.3559x; 1.0128x over previous
//
#include <hip/hip_runtime.h>
#include <hip/hip_bf16.h>

#define SEQ 2048
#define EMB 128
#define KT 64
#define QT 64
#define NT 256
#define NITER (SEQ / KT)

typedef __attribute__((ext_vector_type(8))) short short8;
typedef __attribute__((ext_vector_type(4))) short sh4;
typedef __attribute__((ext_vector_type(4))) float floatx4;
typedef __attribute__((ext_vector_type(4))) unsigned short ushort4_t;

#if __has_builtin(__builtin_amdgcn_mfma_f32_16x16x16_bf16)
#define MFMA16(a, b, c) __builtin_amdgcn_mfma_f32_16x16x16_bf16(a, b, c, 0, 0, 0)
#elif __has_builtin(__builtin_amdgcn_mfma_f32_16x16x16bf16_1k)
#define MFMA16(a, b, c) __builtin_amdgcn_mfma_f32_16x16x16bf16_1k(a, b, c, 0, 0, 0)
#else
__device__ static inline floatx4 MFMA16(sh4, sh4, floatx4 c) { return c; }
#endif

__device__ __forceinline__ unsigned short f2bf(float x) {
  union { float f; unsigned u; } c; c.f = x;
  return (unsigned short)((c.u + 0x7fffu + ((c.u >> 16) & 1u)) >> 16);
}
// packed f32x2 -> bf16x2 via the documented HIP API (RNE, == packbf bitwise);
// lowers to v_cvt_pk_bf16_f32 where available (R4's hand asm is dead — NaN'd).
__device__ __forceinline__ unsigned packbf2(float a, float b) {
  union { __hip_bfloat162 h; unsigned u; } c;
  c.h = __float22bfloat162_rn(float2{a, b});
  return c.u;
}

// ---- fused pre-pass: K fp32->bf16 cvt  +  V fp32 -> Vt bf16 transpose ----
// (R12 WIN version: V columns permuted within each 64-tile so a PV lane's 8
//  shorts are contiguous: col' = g*32 + quad*8 + mt*4 + j.)
__global__ void prep_kernel(const float* __restrict__ K, unsigned short* __restrict__ Kb,
                            const float* __restrict__ V, unsigned short* __restrict__ Vtb,
                            int nblkK) {
  const int tid = threadIdx.x;
  if ((int)blockIdx.x < nblkK) {
    int i = blockIdx.x * NT + tid;
    float4 v = ((const float4*)K)[i];
    ((ushort4_t*)Kb)[i] = (ushort4_t){f2bf(v.x), f2bf(v.y), f2bf(v.z), f2bf(v.w)};
    return;
  }
  const int rb = blockIdx.x - nblkK;
  const int s0 = (rb & 31) * 64;
  const int e0 = ((rb >> 5) & 1) * 64;
  const int b  = rb >> 6;
  const float* src = V + (size_t)b * SEQ * EMB;
  unsigned short* dst = Vtb + (size_t)b * EMB * SEQ;
  const int k = (tid & 15) * 4;
  const int e = (tid >> 4) * 4;
  const int kp = (k & 32) + (((k >> 2) & 3) * 8) + (((k >> 4) & 1) * 4);
  const float* vb = src + (size_t)(s0 + k) * EMB + e0 + e;
  float4 r0 = *(const float4*)(vb);
  float4 r1 = *(const float4*)(vb + EMB);
  float4 r2 = *(const float4*)(vb + 2 * EMB);
  float4 r3 = *(const float4*)(vb + 3 * EMB);
  unsigned short* d0 = dst + (size_t)(e0 + e) * SEQ + s0 + kp;
  *(ushort4_t*)(d0)           = (ushort4_t){f2bf(r0.x), f2bf(r1.x), f2bf(r2.x), f2bf(r3.x)};
  *(ushort4_t*)(d0 + SEQ)     = (ushort4_t){f2bf(r0.y), f2bf(r1.y), f2bf(r2.y), f2bf(r3.y)};
  *(ushort4_t*)(d0 + 2 * SEQ) = (ushort4_t){f2bf(r0.z), f2bf(r1.z), f2bf(r2.z), f2bf(r3.z)};
  *(ushort4_t*)(d0 + 3 * SEQ) = (ushort4_t){f2bf(r0.w), f2bf(r1.w), f2bf(r2.w), f2bf(r3.w)};
}

// ---- main kernel: R12 WIN structure (4 waves 2x2, V staged + b128 pulls,
//      static 2x-unroll, ping-pong regs, setprio). DELTAS vs R12:
//      (a) packbf -> __float22bfloat162_rn (VALU cut on softmax pack);
//      (b) XCD-aware bijective block swizzle: batches 2j,2j+1 -> XCD j, so
//          each XCD's K/V working set (2MB) is L2-resident. ----
__global__ __launch_bounds__(NT, 2)
void fattn7(const float* __restrict__ Qp, const unsigned short* __restrict__ Kb,
            const unsigned short* __restrict__ Vtb, float* __restrict__ Op) {
  __shared__ __align__(16) unsigned char smem[65536];
  unsigned short* Ks = (unsigned short*)smem;            // [2][KT][EMB] 32 KB
  unsigned short* Vs = Ks + 2 * KT * EMB;                // [2][EMB][KT] 32 KB
  float* Ored = (float*)smem;                            // [2][32][132] (epilogue alias)
  float* lred = (float*)(smem + 2 * 32 * 132 * 4);       // [2][32]

  const int tid  = threadIdx.x;
  const int lane = tid & 63;
  const int w    = tid >> 6;
  const int n16  = lane & 15, quad = lane >> 4;
  const int wq   = w & 1;
  const int wk   = w >> 1;
  // XCD-aware bijective swizzle (nwg % 8 == 0: nwg = 32*B)
  const int bid = blockIdx.x;
  const int cpx = (int)(gridDim.x >> 3);
  const int wg  = (bid & 7) * cpx + (bid >> 3);
  const int b   = wg >> 5, q0 = (wg & 31) * QT;
  const size_t bo = (size_t)b * SEQ * EMB;

  auto* ks3 = (__attribute__((address_space(3))) unsigned short*)Ks;
  auto* vs3 = (__attribute__((address_space(3))) unsigned short*)Vs;

  const int krw = tid >> 4, kgs = tid & 15;
  const int vrw = tid >> 3, vgs = tid & 7;
  const unsigned short* pK = Kb + bo + (size_t)krw * EMB + (size_t)((kgs ^ (krw & 7)) * 8);
  const unsigned short* pV = Vtb + bo + (size_t)vrw * SEQ + (size_t)((vgs ^ (vrw & 7)) * 8);

  short8 qf[2][4];
#pragma unroll
  for (int nt = 0; nt < 2; ++nt) {
    const float* qr = Qp + bo + (size_t)(q0 + wq * 32 + nt * 16 + n16) * EMB + quad * 8;
#pragma unroll
    for (int e = 0; e < 4; ++e) {
      float4 x = *(const float4*)(qr + e * 32);
      float4 y = *(const float4*)(qr + e * 32 + 4);
      qf[nt][e] = (short8){(short)f2bf(x.x), (short)f2bf(x.y), (short)f2bf(x.z), (short)f2bf(x.w),
                           (short)f2bf(y.x), (short)f2bf(y.y), (short)f2bf(y.z), (short)f2bf(y.w)};
    }
  }

  int koff[4];
#pragma unroll
  for (int e = 0; e < 4; ++e) koff[e] = ((e * 4 + quad) ^ (n16 & 7)) * 8;
  // V b128 read: global 16B-chunk (wk*4+quad) of row t*16+n16, XOR staging swizzle
  const int voff = ((wk * 4 + quad) ^ (n16 & 7)) * 8;

  floatx4 o[8][2];
#pragma unroll
  for (int t = 0; t < 8; ++t)
#pragma unroll
    for (int nt = 0; nt < 2; ++nt) o[t][nt] = (floatx4){0.f, 0.f, 0.f, 0.f};
  float lp[2] = {0.f, 0.f};

  const float SCALE = 0.08838834764831845f;
  const float L2E = 1.4426950408889634f;
  const float C1 = SCALE * L2E;

  auto issue = [&](int buf) {
    auto* kb = ks3 + buf * (KT * EMB) + w * 512;
    auto* vb = vs3 + buf * (EMB * KT) + w * 512;
    const unsigned short* gv = pV;
#pragma unroll
    for (int j = 0; j < 4; ++j) {
      __builtin_amdgcn_global_load_lds((const __attribute__((address_space(1))) void*)pK,
                                       (__attribute__((address_space(3))) void*)(kb + j * 2048), 16, 0, 0);
      pK += 2048;
      __builtin_amdgcn_global_load_lds((const __attribute__((address_space(1))) void*)gv,
                                       (__attribute__((address_space(3))) void*)(vb + j * 2048), 16, 0, 0);
      gv += 32 * SEQ;
    }
    pV += KT;
  };

  issue(0);

  // named ping-pong state: B-slots are "prev" for tile 0
  short8 vstA[8], vstB[8];
  unsigned pstA[2][2][2], pstB[2][2][2];
#pragma unroll
  for (int t = 0; t < 8; ++t) vstB[t] = (short8){0, 0, 0, 0, 0, 0, 0, 0};
#pragma unroll
  for (int mt = 0; mt < 2; ++mt)
#pragma unroll
    for (int nt = 0; nt < 2; ++nt) { pstB[mt][nt][0] = 0; pstB[mt][nt][1] = 0; }

#define FA_BODY(CUR, VC, VP, PC, PP)                                                     \
  {                                                                                      \
    floatx4 s[2][2];                                                                     \
    _Pragma("unroll") for (int mt = 0; mt < 2; ++mt)                                     \
      _Pragma("unroll") for (int nt = 0; nt < 2; ++nt)                                   \
        s[mt][nt] = (floatx4){0.f, 0.f, 0.f, 0.f};                                       \
    const unsigned short* kbase = Ks + (CUR) * (KT * EMB);                               \
    __builtin_amdgcn_s_setprio(1);                                                       \
    _Pragma("unroll") for (int e = 0; e < 4; ++e) {                                      \
      _Pragma("unroll") for (int mt = 0; mt < 2; ++mt) {                                 \
        short8 ak = *(const short8*)(kbase + (wk * 32 + mt * 16 + n16) * EMB + koff[e]); \
        s[mt][0] = __builtin_amdgcn_mfma_f32_16x16x32_bf16(ak, qf[0][e], s[mt][0], 0, 0, 0); \
        s[mt][1] = __builtin_amdgcn_mfma_f32_16x16x32_bf16(ak, qf[1][e], s[mt][1], 0, 0, 0); \
      }                                                                                  \
    }                                                                                    \
    const unsigned short* vbase = Vs + (CUR) * (EMB * KT);                               \
    _Pragma("unroll") for (int t = 0; t < 8; ++t)                                        \
      VC[t] = *(const short8*)(vbase + (t * 16 + n16) * KT + voff);                      \
    sh4 pb[2][2];                                                                        \
    _Pragma("unroll") for (int mt = 0; mt < 2; ++mt)                                     \
      _Pragma("unroll") for (int nt = 0; nt < 2; ++nt) {                                 \
        union { unsigned u[2]; sh4 v; } cc;                                              \
        cc.u[0] = PP[mt][nt][0];                                                         \
        cc.u[1] = PP[mt][nt][1];                                                         \
        pb[mt][nt] = cc.v;                                                               \
      }                                                                                  \
    _Pragma("unroll") for (int t = 0; t < 8; ++t) {                                      \
      sh4 vlo = __builtin_shufflevector(VP[t], VP[t], 0, 1, 2, 3);                       \
      sh4 vhi = __builtin_shufflevector(VP[t], VP[t], 4, 5, 6, 7);                       \
      _Pragma("unroll") for (int nt = 0; nt < 2; ++nt) {                                 \
        o[t][nt] = MFMA16(vlo, pb[0][nt], o[t][nt]);                                     \
        o[t][nt] = MFMA16(vhi, pb[1][nt], o[t][nt]);                                     \
      }                                                                                  \
    }                                                                                    \
    __builtin_amdgcn_s_setprio(0);                                                       \
    _Pragma("unroll") for (int mt = 0; mt < 2; ++mt)                                     \
      _Pragma("unroll") for (int nt = 0; nt < 2; ++nt) {                                 \
        float p0 = __builtin_amdgcn_exp2f(s[mt][nt][0] * C1);                            \
        float p1 = __builtin_amdgcn_exp2f(s[mt][nt][1] * C1);                            \
        float p2 = __builtin_amdgcn_exp2f(s[mt][nt][2] * C1);                            \
        float p3 = __builtin_amdgcn_exp2f(s[mt][nt][3] * C1);                            \
        lp[nt] += (p0 + p1) + (p2 + p3);                                                 \
        PC[mt][nt][0] = packbf2(p0, p1);                                                 \
        PC[mt][nt][1] = packbf2(p2, p3);                                                 \
      }                                                                                  \
  }

  for (int it2 = 0; it2 < NITER / 2; ++it2) {
    __syncthreads();
    issue(1);
    FA_BODY(0, vstA, vstB, pstA, pstB)
    __syncthreads();
    if (it2 + 1 < NITER / 2) issue(0);
    FA_BODY(1, vstB, vstA, pstB, pstA)
  }

  // ---- trailing PV for the last tile (B-slots) ----
  {
    sh4 pb[2][2];
#pragma unroll
    for (int mt = 0; mt < 2; ++mt)
#pragma unroll
      for (int nt = 0; nt < 2; ++nt) {
        union { unsigned u[2]; sh4 v; } cc;
        cc.u[0] = pstB[mt][nt][0];
        cc.u[1] = pstB[mt][nt][1];
        pb[mt][nt] = cc.v;
      }
#pragma unroll
    for (int t = 0; t < 8; ++t) {
      sh4 vlo = __builtin_shufflevector(vstB[t], vstB[t], 0, 1, 2, 3);
      sh4 vhi = __builtin_shufflevector(vstB[t], vstB[t], 4, 5, 6, 7);
#pragma unroll
      for (int nt = 0; nt < 2; ++nt) {
        o[t][nt] = MFMA16(vlo, pb[0][nt], o[t][nt]);
        o[t][nt] = MFMA16(vhi, pb[1][nt], o[t][nt]);
      }
    }
  }

  // ---- epilogue: reduce across k-halves via LDS (aliased over staging) ----
#pragma unroll
  for (int nt = 0; nt < 2; ++nt) {
    lp[nt] += __shfl_xor(lp[nt], 16);
    lp[nt] += __shfl_xor(lp[nt], 32);
  }
  __syncthreads();
  if (wk) {
#pragma unroll
    for (int t = 0; t < 8; ++t)
#pragma unroll
      for (int nt = 0; nt < 2; ++nt)
        *(floatx4*)&Ored[((wq * 32) + nt * 16 + n16) * 132 + t * 16 + quad * 4] = o[t][nt];
    if (quad == 0) {
      lred[wq * 32 + n16] = lp[0];
      lred[wq * 32 + 16 + n16] = lp[1];
    }
  }
  __syncthreads();
  if (!wk) {
    float inv[2];
#pragma unroll
    for (int nt = 0; nt < 2; ++nt)
      inv[nt] = 1.0f / (lp[nt] + lred[wq * 32 + nt * 16 + n16]);
#pragma unroll
    for (int t = 0; t < 8; ++t)
#pragma unroll
      for (int nt = 0; nt < 2; ++nt) {
        floatx4 r = *(const floatx4*)&Ored[((wq * 32) + nt * 16 + n16) * 132 + t * 16 + quad * 4];
        const int q = q0 + wq * 32 + nt * 16 + n16;
        float4 st = {(o[t][nt][0] + r[0]) * inv[nt], (o[t][nt][1] + r[1]) * inv[nt],
                     (o[t][nt][2] + r[2]) * inv[nt], (o[t][nt][3] + r[3]) * inv[nt]};
        *(float4*)(Op + bo + (size_t)q * EMB + t * 16 + quad * 4) = st;
      }
  }
}

extern "C" void kernel_launch(void* const* d_in, const int* in_sizes, int n_in,
                              void* d_out, int out_size, void* d_ws, size_t ws_size,
                              hipStream_t stream) {
  const float* Q = (const float*)d_in[0];
  const float* K = (const float*)d_in[1];
  const float* V = (const float*)d_in[2];
  float* O = (float*)d_out;
  const int B = in_sizes[0] / (SEQ * EMB);
  const size_t tsz = (size_t)B * SEQ * EMB;

  unsigned short* Kb = (unsigned short*)d_ws;
  unsigned short* Vtb = Kb + tsz;

  const int nblkK = (int)(tsz / 4 / NT);
  const int nblkV = (SEQ / 64) * (EMB / 64) * B;
  prep_kernel<<<nblkK + nblkV, NT, 0, stream>>>(K, Kb, V, Vtb, nblkK);
  fattn7<<<dim3((SEQ / QT) * B), NT, 0, stream>>>(Q, Kb, Vtb, O);
}

// Round 14
// 137.111 us; speedup vs baseline: 2.3930x; 1.0157x over previous
//
#include <hip/hip_runtime.h>
#include <hip/hip_bf16.h>

#define SEQ 2048
#define EMB 128
#define KT 64
#define QT 64
#define NT 256
#define NITER (SEQ / KT)

typedef __attribute__((ext_vector_type(8))) short short8;
typedef __attribute__((ext_vector_type(4))) short sh4;
typedef __attribute__((ext_vector_type(4))) float floatx4;
typedef __attribute__((ext_vector_type(4))) unsigned short ushort4_t;

#if __has_builtin(__builtin_amdgcn_mfma_f32_16x16x16_bf16)
#define MFMA16(a, b, c) __builtin_amdgcn_mfma_f32_16x16x16_bf16(a, b, c, 0, 0, 0)
#elif __has_builtin(__builtin_amdgcn_mfma_f32_16x16x16bf16_1k)
#define MFMA16(a, b, c) __builtin_amdgcn_mfma_f32_16x16x16bf16_1k(a, b, c, 0, 0, 0)
#else
__device__ static inline floatx4 MFMA16(sh4, sh4, floatx4 c) { return c; }
#endif

__device__ __forceinline__ unsigned short f2bf(float x) {
  union { float f; unsigned u; } c; c.f = x;
  return (unsigned short)((c.u + 0x7fffu + ((c.u >> 16) & 1u)) >> 16);
}
// packed f32x2 -> bf16x2 via documented HIP API (RNE, == f2bf bitwise)
__device__ __forceinline__ unsigned packbf2(float a, float b) {
  union { __hip_bfloat162 h; unsigned u; } c;
  c.h = __float22bfloat162_rn(float2{a, b});
  return c.u;
}

// ---- fused pre-pass: K fp32->bf16 cvt  +  V fp32 -> Vt bf16 transpose ----
// (R12 WIN: V columns permuted within each 64-tile, col' = g*32+quad*8+mt*4+j)
__global__ void prep_kernel(const float* __restrict__ K, unsigned short* __restrict__ Kb,
                            const float* __restrict__ V, unsigned short* __restrict__ Vtb,
                            int nblkK) {
  const int tid = threadIdx.x;
  if ((int)blockIdx.x < nblkK) {
    int i = blockIdx.x * NT + tid;
    float4 v = ((const float4*)K)[i];
    ((ushort4_t*)Kb)[i] = (ushort4_t){f2bf(v.x), f2bf(v.y), f2bf(v.z), f2bf(v.w)};
    return;
  }
  const int rb = blockIdx.x - nblkK;
  const int s0 = (rb & 31) * 64;
  const int e0 = ((rb >> 5) & 1) * 64;
  const int b  = rb >> 6;
  const float* src = V + (size_t)b * SEQ * EMB;
  unsigned short* dst = Vtb + (size_t)b * EMB * SEQ;
  const int k = (tid & 15) * 4;
  const int e = (tid >> 4) * 4;
  const int kp = (k & 32) + (((k >> 2) & 3) * 8) + (((k >> 4) & 1) * 4);
  const float* vb = src + (size_t)(s0 + k) * EMB + e0 + e;
  float4 r0 = *(const float4*)(vb);
  float4 r1 = *(const float4*)(vb + EMB);
  float4 r2 = *(const float4*)(vb + 2 * EMB);
  float4 r3 = *(const float4*)(vb + 3 * EMB);
  unsigned short* d0 = dst + (size_t)(e0 + e) * SEQ + s0 + kp;
  *(ushort4_t*)(d0)           = (ushort4_t){f2bf(r0.x), f2bf(r1.x), f2bf(r2.x), f2bf(r3.x)};
  *(ushort4_t*)(d0 + SEQ)     = (ushort4_t){f2bf(r0.y), f2bf(r1.y), f2bf(r2.y), f2bf(r3.y)};
  *(ushort4_t*)(d0 + 2 * SEQ) = (ushort4_t){f2bf(r0.z), f2bf(r1.z), f2bf(r2.z), f2bf(r3.z)};
  *(ushort4_t*)(d0 + 3 * SEQ) = (ushort4_t){f2bf(r0.w), f2bf(r1.w), f2bf(r2.w), f2bf(r3.w)};
}

// ---- main kernel: R13 WIN structure (4 waves 2x2, V staged + b128 pulls,
//      static 2x-unroll, ping-pong regs, packbf2, XCD swizzle).
//      THIS ROUND'S ONLY DELTA: s_setprio REMOVED (m190: negative in
//      barrier-synced lockstep regime; was never isolated). ----
__global__ __launch_bounds__(NT, 2)
void fattn7(const float* __restrict__ Qp, const unsigned short* __restrict__ Kb,
            const unsigned short* __restrict__ Vtb, float* __restrict__ Op) {
  __shared__ __align__(16) unsigned char smem[65536];
  unsigned short* Ks = (unsigned short*)smem;            // [2][KT][EMB] 32 KB
  unsigned short* Vs = Ks + 2 * KT * EMB;                // [2][EMB][KT] 32 KB
  float* Ored = (float*)smem;                            // [2][32][132] (epilogue alias)
  float* lred = (float*)(smem + 2 * 32 * 132 * 4);       // [2][32]

  const int tid  = threadIdx.x;
  const int lane = tid & 63;
  const int w    = tid >> 6;
  const int n16  = lane & 15, quad = lane >> 4;
  const int wq   = w & 1;
  const int wk   = w >> 1;
  // XCD-aware bijective swizzle (nwg % 8 == 0: nwg = 32*B)
  const int bid = blockIdx.x;
  const int cpx = (int)(gridDim.x >> 3);
  const int wg  = (bid & 7) * cpx + (bid >> 3);
  const int b   = wg >> 5, q0 = (wg & 31) * QT;
  const size_t bo = (size_t)b * SEQ * EMB;

  auto* ks3 = (__attribute__((address_space(3))) unsigned short*)Ks;
  auto* vs3 = (__attribute__((address_space(3))) unsigned short*)Vs;

  const int krw = tid >> 4, kgs = tid & 15;
  const int vrw = tid >> 3, vgs = tid & 7;
  const unsigned short* pK = Kb + bo + (size_t)krw * EMB + (size_t)((kgs ^ (krw & 7)) * 8);
  const unsigned short* pV = Vtb + bo + (size_t)vrw * SEQ + (size_t)((vgs ^ (vrw & 7)) * 8);

  short8 qf[2][4];
#pragma unroll
  for (int nt = 0; nt < 2; ++nt) {
    const float* qr = Qp + bo + (size_t)(q0 + wq * 32 + nt * 16 + n16) * EMB + quad * 8;
#pragma unroll
    for (int e = 0; e < 4; ++e) {
      float4 x = *(const float4*)(qr + e * 32);
      float4 y = *(const float4*)(qr + e * 32 + 4);
      qf[nt][e] = (short8){(short)f2bf(x.x), (short)f2bf(x.y), (short)f2bf(x.z), (short)f2bf(x.w),
                           (short)f2bf(y.x), (short)f2bf(y.y), (short)f2bf(y.z), (short)f2bf(y.w)};
    }
  }

  int koff[4];
#pragma unroll
  for (int e = 0; e < 4; ++e) koff[e] = ((e * 4 + quad) ^ (n16 & 7)) * 8;
  // V b128 read: global 16B-chunk (wk*4+quad) of row t*16+n16, XOR staging swizzle
  const int voff = ((wk * 4 + quad) ^ (n16 & 7)) * 8;

  floatx4 o[8][2];
#pragma unroll
  for (int t = 0; t < 8; ++t)
#pragma unroll
    for (int nt = 0; nt < 2; ++nt) o[t][nt] = (floatx4){0.f, 0.f, 0.f, 0.f};
  float lp[2] = {0.f, 0.f};

  const float SCALE = 0.08838834764831845f;
  const float L2E = 1.4426950408889634f;
  const float C1 = SCALE * L2E;

  auto issue = [&](int buf) {
    auto* kb = ks3 + buf * (KT * EMB) + w * 512;
    auto* vb = vs3 + buf * (EMB * KT) + w * 512;
    const unsigned short* gv = pV;
#pragma unroll
    for (int j = 0; j < 4; ++j) {
      __builtin_amdgcn_global_load_lds((const __attribute__((address_space(1))) void*)pK,
                                       (__attribute__((address_space(3))) void*)(kb + j * 2048), 16, 0, 0);
      pK += 2048;
      __builtin_amdgcn_global_load_lds((const __attribute__((address_space(1))) void*)gv,
                                       (__attribute__((address_space(3))) void*)(vb + j * 2048), 16, 0, 0);
      gv += 32 * SEQ;
    }
    pV += KT;
  };

  issue(0);

  // named ping-pong state: B-slots are "prev" for tile 0
  short8 vstA[8], vstB[8];
  unsigned pstA[2][2][2], pstB[2][2][2];
#pragma unroll
  for (int t = 0; t < 8; ++t) vstB[t] = (short8){0, 0, 0, 0, 0, 0, 0, 0};
#pragma unroll
  for (int mt = 0; mt < 2; ++mt)
#pragma unroll
    for (int nt = 0; nt < 2; ++nt) { pstB[mt][nt][0] = 0; pstB[mt][nt][1] = 0; }

#define FA_BODY(CUR, VC, VP, PC, PP)                                                     \
  {                                                                                      \
    floatx4 s[2][2];                                                                     \
    _Pragma("unroll") for (int mt = 0; mt < 2; ++mt)                                     \
      _Pragma("unroll") for (int nt = 0; nt < 2; ++nt)                                   \
        s[mt][nt] = (floatx4){0.f, 0.f, 0.f, 0.f};                                       \
    const unsigned short* kbase = Ks + (CUR) * (KT * EMB);                               \
    _Pragma("unroll") for (int e = 0; e < 4; ++e) {                                      \
      _Pragma("unroll") for (int mt = 0; mt < 2; ++mt) {                                 \
        short8 ak = *(const short8*)(kbase + (wk * 32 + mt * 16 + n16) * EMB + koff[e]); \
        s[mt][0] = __builtin_amdgcn_mfma_f32_16x16x32_bf16(ak, qf[0][e], s[mt][0], 0, 0, 0); \
        s[mt][1] = __builtin_amdgcn_mfma_f32_16x16x32_bf16(ak, qf[1][e], s[mt][1], 0, 0, 0); \
      }                                                                                  \
    }                                                                                    \
    const unsigned short* vbase = Vs + (CUR) * (EMB * KT);                               \
    _Pragma("unroll") for (int t = 0; t < 8; ++t)                                        \
      VC[t] = *(const short8*)(vbase + (t * 16 + n16) * KT + voff);                      \
    sh4 pb[2][2];                                                                        \
    _Pragma("unroll") for (int mt = 0; mt < 2; ++mt)                                     \
      _Pragma("unroll") for (int nt = 0; nt < 2; ++nt) {                                 \
        union { unsigned u[2]; sh4 v; } cc;                                              \
        cc.u[0] = PP[mt][nt][0];                                                         \
        cc.u[1] = PP[mt][nt][1];                                                         \
        pb[mt][nt] = cc.v;                                                               \
      }                                                                                  \
    _Pragma("unroll") for (int t = 0; t < 8; ++t) {                                      \
      sh4 vlo = __builtin_shufflevector(VP[t], VP[t], 0, 1, 2, 3);                       \
      sh4 vhi = __builtin_shufflevector(VP[t], VP[t], 4, 5, 6, 7);                       \
      _Pragma("unroll") for (int nt = 0; nt < 2; ++nt) {                                 \
        o[t][nt] = MFMA16(vlo, pb[0][nt], o[t][nt]);                                     \
        o[t][nt] = MFMA16(vhi, pb[1][nt], o[t][nt]);                                     \
      }                                                                                  \
    }                                                                                    \
    _Pragma("unroll") for (int mt = 0; mt < 2; ++mt)                                     \
      _Pragma("unroll") for (int nt = 0; nt < 2; ++nt) {                                 \
        float p0 = __builtin_amdgcn_exp2f(s[mt][nt][0] * C1);                            \
        float p1 = __builtin_amdgcn_exp2f(s[mt][nt][1] * C1);                            \
        float p2 = __builtin_amdgcn_exp2f(s[mt][nt][2] * C1);                            \
        float p3 = __builtin_amdgcn_exp2f(s[mt][nt][3] * C1);                            \
        lp[nt] += (p0 + p1) + (p2 + p3);                                                 \
        PC[mt][nt][0] = packbf2(p0, p1);                                                 \
        PC[mt][nt][1] = packbf2(p2, p3);                                                 \
      }                                                                                  \
  }

  for (int it2 = 0; it2 < NITER / 2; ++it2) {
    __syncthreads();
    issue(1);
    FA_BODY(0, vstA, vstB, pstA, pstB)
    __syncthreads();
    if (it2 + 1 < NITER / 2) issue(0);
    FA_BODY(1, vstB, vstA, pstB, pstA)
  }

  // ---- trailing PV for the last tile (B-slots) ----
  {
    sh4 pb[2][2];
#pragma unroll
    for (int mt = 0; mt < 2; ++mt)
#pragma unroll
      for (int nt = 0; nt < 2; ++nt) {
        union { unsigned u[2]; sh4 v; } cc;
        cc.u[0] = pstB[mt][nt][0];
        cc.u[1] = pstB[mt][nt][1];
        pb[mt][nt] = cc.v;
      }
#pragma unroll
    for (int t = 0; t < 8; ++t) {
      sh4 vlo = __builtin_shufflevector(vstB[t], vstB[t], 0, 1, 2, 3);
      sh4 vhi = __builtin_shufflevector(vstB[t], vstB[t], 4, 5, 6, 7);
#pragma unroll
      for (int nt = 0; nt < 2; ++nt) {
        o[t][nt] = MFMA16(vlo, pb[0][nt], o[t][nt]);
        o[t][nt] = MFMA16(vhi, pb[1][nt], o[t][nt]);
      }
    }
  }

  // ---- epilogue: reduce across k-halves via LDS (aliased over staging) ----
#pragma unroll
  for (int nt = 0; nt < 2; ++nt) {
    lp[nt] += __shfl_xor(lp[nt], 16);
    lp[nt] += __shfl_xor(lp[nt], 32);
  }
  __syncthreads();
  if (wk) {
#pragma unroll
    for (int t = 0; t < 8; ++t)
#pragma unroll
      for (int nt = 0; nt < 2; ++nt)
        *(floatx4*)&Ored[((wq * 32) + nt * 16 + n16) * 132 + t * 16 + quad * 4] = o[t][nt];
    if (quad == 0) {
      lred[wq * 32 + n16] = lp[0];
      lred[wq * 32 + 16 + n16] = lp[1];
    }
  }
  __syncthreads();
  if (!wk) {
    float inv[2];
#pragma unroll
    for (int nt = 0; nt < 2; ++nt)
      inv[nt] = 1.0f / (lp[nt] + lred[wq * 32 + nt * 16 + n16]);
#pragma unroll
    for (int t = 0; t < 8; ++t)
#pragma unroll
      for (int nt = 0; nt < 2; ++nt) {
        floatx4 r = *(const floatx4*)&Ored[((wq * 32) + nt * 16 + n16) * 132 + t * 16 + quad * 4];
        const int q = q0 + wq * 32 + nt * 16 + n16;
        float4 st = {(o[t][nt][0] + r[0]) * inv[nt], (o[t][nt][1] + r[1]) * inv[nt],
                     (o[t][nt][2] + r[2]) * inv[nt], (o[t][nt][3] + r[3]) * inv[nt]};
        *(float4*)(Op + bo + (size_t)q * EMB + t * 16 + quad * 4) = st;
      }
  }
}

extern "C" void kernel_launch(void* const* d_in, const int* in_sizes, int n_in,
                              void* d_out, int out_size, void* d_ws, size_t ws_size,
                              hipStream_t stream) {
  const float* Q = (const float*)d_in[0];
  const float* K = (const float*)d_in[1];
  const float* V = (const float*)d_in[2];
  float* O = (float*)d_out;
  const int B = in_sizes[0] / (SEQ * EMB);
  const size_t tsz = (size_t)B * SEQ * EMB;

  unsigned short* Kb = (unsigned short*)d_ws;
  unsigned short* Vtb = Kb + tsz;

  const int nblkK = (int)(tsz / 4 / NT);
  const int nblkV = (SEQ / 64) * (EMB / 64) * B;
  prep_kernel<<<nblkK + nblkV, NT, 0, stream>>>(K, Kb, V, Vtb, nblkK);
  fattn7<<<dim3((SEQ / QT) * B), NT, 0, stream>>>(Q, Kb, Vtb, O);
}